// Round 6
// baseline (361.666 us; speedup 1.0000x reference)
//
#include <hip/hip_runtime.h>
#include <hip/hip_bf16.h>
#include <cstdint>
#include <cstddef>

typedef __bf16 bf16_t;
typedef __bf16 bf16x8 __attribute__((ext_vector_type(8)));
typedef __bf16 bf16x4 __attribute__((ext_vector_type(4)));
typedef float f32x4 __attribute__((ext_vector_type(4)));

#define B_   4
#define T_   32
#define N_   288
#define D_   128
#define H_   4
#define HD_  32
#define BT_  (B_*T_)        // 128
#define NTOK (BT_*N_)       // 36864
#define BTH  (BT_*H_)       // 512

// workspace byte offsets (all 16B-aligned)
#define OFF_Q   ((size_t)0)
#define OFF_K   (OFF_Q  + (size_t)BTH*N_*HD_*2)
#define OFF_VT  (OFF_K  + (size_t)BTH*N_*HD_*2)
#define OFF_CTX (OFF_VT + (size_t)BTH*N_*HD_*2)
#define OFF_WT  (OFF_CTX + (size_t)NTOK*D_*2)
#define OFF_MB  (OFF_WT + (size_t)4*128*128*2)     // 512 heads x 1296 u64 = 5.3 MB

// ---------------------------------------------------------------- kernel 0
__global__ __launch_bounds__(256) void prep_weights(
    const float* __restrict__ Wq, const float* __restrict__ Wk,
    const float* __restrict__ Wv, const float* __restrict__ Wo,
    bf16_t* __restrict__ Wt) {
  int idx = blockIdx.x * 256 + threadIdx.x;     // 0 .. 65535
  int m   = idx >> 14;
  int rem = idx & 16383;
  int col = rem >> 7;
  int k   = rem & 127;
  const float* W = (m == 0) ? Wq : (m == 1) ? Wk : (m == 2) ? Wv : Wo;
  Wt[m * 16384 + col * 128 + k] = (bf16_t)W[k * 128 + col];
}

// ---------------------------------------------------------------- kernel 0b
// Stream the whole 166 MB drop_u once at full occupancy (32 waves/CU, no
// barriers) and ballot-pack keep-bits into a global bitmask. Bit layout is
// identical to attn's old in-LDS mbits64: flat bit index = head*82944 +
// row*288 + col; u64 word = pair*9 + e, bit = lane, where pair = flat row
// pair, e*64+lane = offset within the 576-float row-pair.
__global__ __launch_bounds__(256) void build_mask(
    const float* __restrict__ drop_u, const int* __restrict__ nxp,
    unsigned long long* __restrict__ maskG) {
  const int lane = threadIdx.x & 63;
  const int wv   = (blockIdx.x * 256 + threadIdx.x) >> 6;  // 0..8191
  const int nx   = *nxp;
  const float keepx = 0.9f, keepl = 0.7f;
  // 73728 row-pairs total, 9 consecutive pairs per wave
#pragma unroll 1
  for (int it = 0; it < 9; ++it) {
    const int p    = wv * 9 + it;                // pair index
    const int rowg = (p % 144) * 2;              // within-head row of pair
    const float* Up = drop_u + (size_t)p * 576;
    float u[9];
#pragma unroll
    for (int e = 0; e < 9; ++e) u[e] = Up[e * 64 + lane];
    unsigned long long bal[9];
#pragma unroll
    for (int e = 0; e < 9; ++e) {
      int off = e * 64 + lane;                   // 0..575
      int rin = off >= 288 ? 1 : 0;
      int col = off - rin * 288;
      int row = rowg + rin;
      float kp = (row < nx && col < nx) ? keepx : keepl;
      bal[e] = __ballot(u[e] < kp);
    }
    if (lane == 0) {
#pragma unroll
      for (int e = 0; e < 9; ++e) maskG[(size_t)p * 9 + e] = bal[e];
    }
  }
}

// ---------------------------------------------------------------- kernel 1
// QKV projection: x(fp32) @ W -> Q,K [bth][n][hd] bf16 ; V transposed [bth][hd][n]
__global__ __launch_bounds__(256) void qkv_proj(
    const float* __restrict__ x, const bf16_t* __restrict__ Wt,
    bf16_t* __restrict__ Q, bf16_t* __restrict__ K, bf16_t* __restrict__ VT) {
  const int lane = threadIdx.x & 63;
  const int wid  = threadIdx.x >> 6;           // 0..3
  const int lr   = lane & 15, lg = lane >> 4;
  const int tokbase = blockIdx.x * 64 + wid * 16;

  bf16x8 a[4];
  const float* xr = x + (size_t)(tokbase + lr) * D_ + lg * 8;
#pragma unroll
  for (int ks = 0; ks < 4; ++ks) {
    float4 f0 = *reinterpret_cast<const float4*>(xr + ks * 32);
    float4 f1 = *reinterpret_cast<const float4*>(xr + ks * 32 + 4);
    bf16x8 v;
    v[0] = (bf16_t)f0.x; v[1] = (bf16_t)f0.y; v[2] = (bf16_t)f0.z; v[3] = (bf16_t)f0.w;
    v[4] = (bf16_t)f1.x; v[5] = (bf16_t)f1.y; v[6] = (bf16_t)f1.z; v[7] = (bf16_t)f1.w;
    a[ks] = v;
  }

  const int tok0 = tokbase + lg * 4;
  const int bt   = tok0 / N_;
  const int n0   = tok0 - bt * N_;

#pragma unroll
  for (int m = 0; m < 3; ++m) {
    const bf16_t* Wm = Wt + m * 16384;
#pragma unroll
    for (int ct = 0; ct < 8; ++ct) {
      const int col = ct * 16 + lr;
      f32x4 acc = {0.f, 0.f, 0.f, 0.f};
#pragma unroll
      for (int ks = 0; ks < 4; ++ks) {
        bf16x8 b = *reinterpret_cast<const bf16x8*>(Wm + col * D_ + ks * 32 + lg * 8);
        acc = __builtin_amdgcn_mfma_f32_16x16x32_bf16(a[ks], b, acc, 0, 0, 0);
      }
      const int h = col >> 5, dh = col & 31;
      if (m == 2) {
        bf16x4 pk;
        pk[0] = (bf16_t)acc[0]; pk[1] = (bf16_t)acc[1];
        pk[2] = (bf16_t)acc[2]; pk[3] = (bf16_t)acc[3];
        *reinterpret_cast<bf16x4*>(
            VT + ((size_t)(bt * H_ + h) * HD_ + dh) * N_ + n0) = pk;
      } else {
        bf16_t* P = (m == 0) ? Q : K;
        size_t base = ((size_t)(bt * H_ + h) * N_ + n0) * HD_ + dh;
        P[base]           = (bf16_t)acc[0];
        P[base + HD_]     = (bf16_t)acc[1];
        P[base + 2 * HD_] = (bf16_t)acc[2];
        P[base + 3 * HD_] = (bf16_t)acc[3];
      }
    }
  }
}

// ---------------------------------------------------------------- kernel 2
// One block per (b,t,h). 6 waves, 3 row-tiles of 16 q-rows each.
// Prologue: coalesced copy of this head's 10.4 KB bitmask into LDS.
// Then: QK^T -> softmax (mask bits from LDS) -> PV (chunked P transpose).
// NOTE: PV chunk loop MUST stay fully unrolled — runtime index into acc[18]
// demotes it to scratch (Rule #20; was 175MB of HBM scratch writebacks).
__global__ __launch_bounds__(384, 2) void attn(
    const bf16_t* __restrict__ Q, const bf16_t* __restrict__ K,
    const bf16_t* __restrict__ VT, const unsigned long long* __restrict__ maskG,
    const int* __restrict__ nxp, bf16_t* __restrict__ CTX) {
  __shared__ bf16_t wlds[6][16][104];                 // per-wave P chunk scratch
  __shared__ unsigned long long mbits64[1296];        // 288*288 bits, row-major

  const int lane = threadIdx.x & 63;
  const int wid  = threadIdx.x >> 6;           // 0..5
  const int lr   = lane & 15, lg = lane >> 4;
  const int bth  = blockIdx.x;
  const int bt   = bth >> 2, h = bth & 3;

  const int   nx    = *nxp;
  const float keepx = 1.0f - 0.1f;
  const float keepl = 1.0f - 0.3f;
  const float nxx   = (float)nx * (float)nx;
  const float ntot  = (float)(N_ * N_);
  const float dropscale = ntot / (nxx * keepx + (ntot - nxx) * keepl);
  const float sc = 0.17677669529663687f;       // 1/sqrt(32)

  const bf16_t* Qh = Q  + (size_t)bth * N_ * HD_;
  const bf16_t* Kh = K  + (size_t)bth * N_ * HD_;
  const bf16_t* Vh = VT + (size_t)bth * HD_ * N_;

  // ---------------- prologue: mask bitmask global -> LDS (coalesced)
  {
    const unsigned int* mg = (const unsigned int*)maskG + (size_t)bth * 2592;
    unsigned int* md = (unsigned int*)mbits64;
    for (int i = threadIdx.x; i < 2592; i += 384) md[i] = mg[i];
  }
  __syncthreads();
  const unsigned int* mb = (const unsigned int*)mbits64;

  // ---------------- attention tiles
  for (int ti = 0; ti < 3; ++ti) {
    const int tile    = wid + ti * 6;            // 0..17
    const int rowbase = tile * 16;

    // QK^T: scores[16 x 288] in accumulators
    bf16x8 a = *reinterpret_cast<const bf16x8*>(Qh + (rowbase + lr) * HD_ + lg * 8);
    f32x4 acc[18];
#pragma unroll
    for (int ct = 0; ct < 18; ++ct) {
      bf16x8 b = *reinterpret_cast<const bf16x8*>(Kh + (ct * 16 + lr) * HD_ + lg * 8);
      f32x4 z = {0.f, 0.f, 0.f, 0.f};
      acc[ct] = __builtin_amdgcn_mfma_f32_16x16x32_bf16(a, b, z, 0, 0, 0);
    }

    // row max (rows = rowbase + lg*4 + r; cols = ct*16 + lr)
    float m[4] = {-1e30f, -1e30f, -1e30f, -1e30f};
#pragma unroll
    for (int ct = 0; ct < 18; ++ct)
#pragma unroll
      for (int r = 0; r < 4; ++r) m[r] = fmaxf(m[r], acc[ct][r]);
#pragma unroll
    for (int i = 1; i < 16; i <<= 1)
#pragma unroll
      for (int r = 0; r < 4; ++r) m[r] = fmaxf(m[r], __shfl_xor(m[r], i));

    // exp + full-row sum + dropout mask from LDS bits
    const int q0 = rowbase + lg * 4;
    float s[4];
#pragma unroll
    for (int r = 0; r < 4; ++r) {
      float acc_s = 0.f;
      unsigned int rd[9];
#pragma unroll
      for (int w9 = 0; w9 < 9; ++w9) rd[w9] = mb[(q0 + r) * 9 + w9];
#pragma unroll
      for (int ct = 0; ct < 18; ++ct) {
        float e = __expf((acc[ct][r] - m[r]) * sc);
        acc_s += e;                              // denominator over ALL entries
        unsigned int bit = (rd[ct >> 1] >> ((ct & 1) * 16 + lr)) & 1u;
        acc[ct][r] = bit ? e : 0.f;
      }
      s[r] = acc_s;
    }
#pragma unroll
    for (int i = 1; i < 16; i <<= 1)
#pragma unroll
      for (int r = 0; r < 4; ++r) s[r] += __shfl_xor(s[r], i);

    float inv[4];
#pragma unroll
    for (int r = 0; r < 4; ++r) inv[r] = dropscale / s[r];

    // PV with chunked P transpose (96 cols per chunk) — FULLY UNROLLED
    f32x4 cd[2] = {{0.f,0.f,0.f,0.f},{0.f,0.f,0.f,0.f}};
#pragma unroll
    for (int chunk = 0; chunk < 3; ++chunk) {
#pragma unroll
      for (int cc = 0; cc < 6; ++cc) {
        const int ct = chunk * 6 + cc;
#pragma unroll
        for (int r = 0; r < 4; ++r)
          wlds[wid][lg * 4 + r][cc * 16 + lr] = (bf16_t)(acc[ct][r] * inv[r]);
      }
#pragma unroll
      for (int dt = 0; dt < 2; ++dt)
#pragma unroll
        for (int k3 = 0; k3 < 3; ++k3) {
          bf16x8 aw = *reinterpret_cast<const bf16x8*>(&wlds[wid][lr][k3 * 32 + lg * 8]);
          bf16x8 bv = *reinterpret_cast<const bf16x8*>(
              Vh + (dt * 16 + lr) * N_ + chunk * 96 + k3 * 32 + lg * 8);
          cd[dt] = __builtin_amdgcn_mfma_f32_16x16x32_bf16(aw, bv, cd[dt], 0, 0, 0);
        }
    }

#pragma unroll
    for (int dt = 0; dt < 2; ++dt) {
      size_t obase = ((size_t)bt * N_ + q0) * D_ + h * HD_ + dt * 16 + lr;
#pragma unroll
      for (int r = 0; r < 4; ++r)
        CTX[obase + (size_t)r * D_] = (bf16_t)cd[dt][r];
    }
  }
}

// ---------------------------------------------------------------- kernel 3
__global__ __launch_bounds__(256) void out_proj(
    const bf16_t* __restrict__ CTX, const bf16_t* __restrict__ Wt,
    const float* __restrict__ bo, float* __restrict__ out) {
  const int lane = threadIdx.x & 63;
  const int wid  = threadIdx.x >> 6;
  const int lr   = lane & 15, lg = lane >> 4;
  const int tokbase = blockIdx.x * 64 + wid * 16;
  const bf16_t* Wo = Wt + 3 * 16384;

  bf16x8 a[4];
#pragma unroll
  for (int ks = 0; ks < 4; ++ks)
    a[ks] = *reinterpret_cast<const bf16x8*>(
        CTX + (size_t)(tokbase + lr) * D_ + ks * 32 + lg * 8);

  const int tok0 = tokbase + lg * 4;
#pragma unroll
  for (int ct = 0; ct < 8; ++ct) {
    const int col = ct * 16 + lr;
    f32x4 acc = {0.f, 0.f, 0.f, 0.f};
#pragma unroll
    for (int ks = 0; ks < 4; ++ks) {
      bf16x8 b = *reinterpret_cast<const bf16x8*>(Wo + col * D_ + ks * 32 + lg * 8);
      acc = __builtin_amdgcn_mfma_f32_16x16x32_bf16(a[ks], b, acc, 0, 0, 0);
    }
    const float bias = bo[col];
    size_t ob = (size_t)tok0 * D_ + col;
#pragma unroll
    for (int r = 0; r < 4; ++r) out[ob + (size_t)r * D_] = acc[r] + bias;
  }
}

// ---------------------------------------------------------------- launcher
extern "C" void kernel_launch(void* const* d_in, const int* in_sizes, int n_in,
                              void* d_out, int out_size, void* d_ws, size_t ws_size,
                              hipStream_t stream) {
  (void)in_sizes; (void)n_in; (void)out_size; (void)ws_size;
  const float* x  = (const float*)d_in[0];
  const float* Wq = (const float*)d_in[1];
  const float* Wk = (const float*)d_in[2];
  const float* Wv = (const float*)d_in[3];
  const float* Wo = (const float*)d_in[4];
  const float* bo = (const float*)d_in[5];
  const float* du = (const float*)d_in[6];
  const int*   nx = (const int*)d_in[7];

  char* ws = (char*)d_ws;
  bf16_t* Qb   = (bf16_t*)(ws + OFF_Q);
  bf16_t* Kb   = (bf16_t*)(ws + OFF_K);
  bf16_t* VTb  = (bf16_t*)(ws + OFF_VT);
  bf16_t* CTXb = (bf16_t*)(ws + OFF_CTX);
  bf16_t* Wt   = (bf16_t*)(ws + OFF_WT);
  unsigned long long* maskG = (unsigned long long*)(ws + OFF_MB);

  build_mask<<<2048, 256, 0, stream>>>(du, nx, maskG);
  prep_weights<<<256, 256, 0, stream>>>(Wq, Wk, Wv, Wo, Wt);
  qkv_proj<<<NTOK / 64, 256, 0, stream>>>(x, Wt, Qb, Kb, VTb);
  attn<<<BTH, 384, 0, stream>>>(Qb, Kb, VTb, maskG, nx, CTXb);
  out_proj<<<NTOK / 64, 256, 0, stream>>>(CTXb, Wt, bo, (float*)d_out);
}

// Round 7
// 349.354 us; speedup vs baseline: 1.0352x; 1.0352x over previous
//
#include <hip/hip_runtime.h>
#include <hip/hip_bf16.h>
#include <cstdint>
#include <cstddef>

typedef __bf16 bf16_t;
typedef __bf16 bf16x8 __attribute__((ext_vector_type(8)));
typedef __bf16 bf16x4 __attribute__((ext_vector_type(4)));
typedef float f32x4 __attribute__((ext_vector_type(4)));

#define B_   4
#define T_   32
#define N_   288
#define D_   128
#define H_   4
#define HD_  32
#define BT_  (B_*T_)        // 128
#define NTOK (BT_*N_)       // 36864
#define BTH  (BT_*H_)       // 512

// workspace byte offsets (all 16B-aligned)
#define OFF_Q   ((size_t)0)
#define OFF_K   (OFF_Q  + (size_t)BTH*N_*HD_*2)
#define OFF_VT  (OFF_K  + (size_t)BTH*N_*HD_*2)
#define OFF_CTX (OFF_VT + (size_t)BTH*N_*HD_*2)
#define OFF_WT  (OFF_CTX + (size_t)NTOK*D_*2)
#define OFF_MB  (OFF_WT + (size_t)4*128*128*2)     // 512 heads x 1296 u64 = 5.3 MB

// ---------------------------------------------------------------- kernel 0
__global__ __launch_bounds__(256) void prep_weights(
    const float* __restrict__ Wq, const float* __restrict__ Wk,
    const float* __restrict__ Wv, const float* __restrict__ Wo,
    bf16_t* __restrict__ Wt) {
  int idx = blockIdx.x * 256 + threadIdx.x;     // 0 .. 65535
  int m   = idx >> 14;
  int rem = idx & 16383;
  int col = rem >> 7;
  int k   = rem & 127;
  const float* W = (m == 0) ? Wq : (m == 1) ? Wk : (m == 2) ? Wv : Wo;
  Wt[m * 16384 + col * 128 + k] = (bf16_t)W[k * 128 + col];
}

// ---------------------------------------------------------------- kernel 0b
// Stream the whole 166 MB drop_u once at full occupancy (32 waves/CU, no
// barriers) and ballot-pack keep-bits into a global bitmask. Bit layout:
// pair p = flat row-pair (head*144 + row/2); u64 word = p*9 + e; bit = lane,
// where e*64+lane = offset within the 576-float row-pair.
__global__ __launch_bounds__(256) void build_mask(
    const float* __restrict__ drop_u, const int* __restrict__ nxp,
    unsigned long long* __restrict__ maskG) {
  const int lane = threadIdx.x & 63;
  const int wv   = (blockIdx.x * 256 + threadIdx.x) >> 6;  // 0..8191
  const int nx   = *nxp;
  const float keepx = 0.9f, keepl = 0.7f;
  // 73728 row-pairs total, 9 consecutive pairs per wave
#pragma unroll 1
  for (int it = 0; it < 9; ++it) {
    const int p    = wv * 9 + it;                // pair index
    const int rowg = (p % 144) * 2;              // within-head row of pair
    const float* Up = drop_u + (size_t)p * 576;
    float u[9];
#pragma unroll
    for (int e = 0; e < 9; ++e) u[e] = Up[e * 64 + lane];
    unsigned long long bal[9];
#pragma unroll
    for (int e = 0; e < 9; ++e) {
      int off = e * 64 + lane;                   // 0..575
      int rin = off >= 288 ? 1 : 0;
      int col = off - rin * 288;
      int row = rowg + rin;
      float kp = (row < nx && col < nx) ? keepx : keepl;
      bal[e] = __ballot(u[e] < kp);
    }
    if (lane == 0) {
#pragma unroll
      for (int e = 0; e < 9; ++e) maskG[(size_t)p * 9 + e] = bal[e];
    }
  }
}

// ---------------------------------------------------------------- kernel 1
// QKV projection: x(fp32) @ W -> Q,K [bth][n][hd] bf16 ; V transposed [bth][hd][n]
__global__ __launch_bounds__(256) void qkv_proj(
    const float* __restrict__ x, const bf16_t* __restrict__ Wt,
    bf16_t* __restrict__ Q, bf16_t* __restrict__ K, bf16_t* __restrict__ VT) {
  const int lane = threadIdx.x & 63;
  const int wid  = threadIdx.x >> 6;           // 0..3
  const int lr   = lane & 15, lg = lane >> 4;
  const int tokbase = blockIdx.x * 64 + wid * 16;

  bf16x8 a[4];
  const float* xr = x + (size_t)(tokbase + lr) * D_ + lg * 8;
#pragma unroll
  for (int ks = 0; ks < 4; ++ks) {
    float4 f0 = *reinterpret_cast<const float4*>(xr + ks * 32);
    float4 f1 = *reinterpret_cast<const float4*>(xr + ks * 32 + 4);
    bf16x8 v;
    v[0] = (bf16_t)f0.x; v[1] = (bf16_t)f0.y; v[2] = (bf16_t)f0.z; v[3] = (bf16_t)f0.w;
    v[4] = (bf16_t)f1.x; v[5] = (bf16_t)f1.y; v[6] = (bf16_t)f1.z; v[7] = (bf16_t)f1.w;
    a[ks] = v;
  }

  const int tok0 = tokbase + lg * 4;
  const int bt   = tok0 / N_;
  const int n0   = tok0 - bt * N_;

#pragma unroll
  for (int m = 0; m < 3; ++m) {
    const bf16_t* Wm = Wt + m * 16384;
#pragma unroll
    for (int ct = 0; ct < 8; ++ct) {
      const int col = ct * 16 + lr;
      f32x4 acc = {0.f, 0.f, 0.f, 0.f};
#pragma unroll
      for (int ks = 0; ks < 4; ++ks) {
        bf16x8 b = *reinterpret_cast<const bf16x8*>(Wm + col * D_ + ks * 32 + lg * 8);
        acc = __builtin_amdgcn_mfma_f32_16x16x32_bf16(a[ks], b, acc, 0, 0, 0);
      }
      const int h = col >> 5, dh = col & 31;
      if (m == 2) {
        bf16x4 pk;
        pk[0] = (bf16_t)acc[0]; pk[1] = (bf16_t)acc[1];
        pk[2] = (bf16_t)acc[2]; pk[3] = (bf16_t)acc[3];
        *reinterpret_cast<bf16x4*>(
            VT + ((size_t)(bt * H_ + h) * HD_ + dh) * N_ + n0) = pk;
      } else {
        bf16_t* P = (m == 0) ? Q : K;
        size_t base = ((size_t)(bt * H_ + h) * N_ + n0) * HD_ + dh;
        P[base]           = (bf16_t)acc[0];
        P[base + HD_]     = (bf16_t)acc[1];
        P[base + 2 * HD_] = (bf16_t)acc[2];
        P[base + 3 * HD_] = (bf16_t)acc[3];
      }
    }
  }
}

// ---------------------------------------------------------------- kernel 2
// Barrier-free attention: one wave = one (bth, tile) task; 9216 tasks,
// 4 independent waves per 256-thread block, NO __syncthreads.
// Mask bits read directly from global maskG (5.3 MB, L2/L3-resident,
// broadcast-uniform within each 16-lane group). LDS = per-wave P-transpose
// scratch only. PV chunk loop fully unrolled (Rule #20: runtime index into
// acc[18] demotes it to scratch -> 175MB HBM writeback storm in R1-R3).
__global__ __launch_bounds__(256, 4) void attn(
    const bf16_t* __restrict__ Q, const bf16_t* __restrict__ K,
    const bf16_t* __restrict__ VT, const unsigned long long* __restrict__ maskG,
    const int* __restrict__ nxp, bf16_t* __restrict__ CTX) {
  __shared__ bf16_t wlds[4][16][104];          // per-wave P chunk scratch

  const int lane = threadIdx.x & 63;
  const int wid  = threadIdx.x >> 6;           // 0..3
  const int lr   = lane & 15, lg = lane >> 4;

  const int gw   = blockIdx.x * 4 + wid;       // 0..9215
  const int bth  = gw / 18;
  const int tile = gw - bth * 18;              // 0..17
  const int bt   = bth >> 2, h = bth & 3;

  const int   nx    = *nxp;
  const float keepx = 1.0f - 0.1f;
  const float keepl = 1.0f - 0.3f;
  const float nxx   = (float)nx * (float)nx;
  const float ntot  = (float)(N_ * N_);
  const float dropscale = ntot / (nxx * keepx + (ntot - nxx) * keepl);
  const float sc = 0.17677669529663687f;       // 1/sqrt(32)

  const bf16_t* Qh = Q  + (size_t)bth * N_ * HD_;
  const bf16_t* Kh = K  + (size_t)bth * N_ * HD_;
  const bf16_t* Vh = VT + (size_t)bth * HD_ * N_;
  const unsigned int* mb = (const unsigned int*)maskG + (size_t)bth * 2592;

  const int rowbase = tile * 16;

  // QK^T: scores[16 x 288] in accumulators
  bf16x8 a = *reinterpret_cast<const bf16x8*>(Qh + (rowbase + lr) * HD_ + lg * 8);
  f32x4 acc[18];
#pragma unroll
  for (int ct = 0; ct < 18; ++ct) {
    bf16x8 b = *reinterpret_cast<const bf16x8*>(Kh + (ct * 16 + lr) * HD_ + lg * 8);
    f32x4 z = {0.f, 0.f, 0.f, 0.f};
    acc[ct] = __builtin_amdgcn_mfma_f32_16x16x32_bf16(a, b, z, 0, 0, 0);
  }

  // row max (rows = rowbase + lg*4 + r; cols = ct*16 + lr)
  float m[4] = {-1e30f, -1e30f, -1e30f, -1e30f};
#pragma unroll
  for (int ct = 0; ct < 18; ++ct)
#pragma unroll
    for (int r = 0; r < 4; ++r) m[r] = fmaxf(m[r], acc[ct][r]);
#pragma unroll
  for (int i = 1; i < 16; i <<= 1)
#pragma unroll
    for (int r = 0; r < 4; ++r) m[r] = fmaxf(m[r], __shfl_xor(m[r], i));

  // exp + full-row sum + dropout mask bits (global, group-uniform)
  const int q0 = rowbase + lg * 4;
  float s[4];
#pragma unroll
  for (int r = 0; r < 4; ++r) {
    float acc_s = 0.f;
    unsigned int rd[9];
#pragma unroll
    for (int w9 = 0; w9 < 9; ++w9) rd[w9] = mb[(q0 + r) * 9 + w9];
#pragma unroll
    for (int ct = 0; ct < 18; ++ct) {
      float e = __expf((acc[ct][r] - m[r]) * sc);
      acc_s += e;                              // denominator over ALL entries
      unsigned int bit = (rd[ct >> 1] >> ((ct & 1) * 16 + lr)) & 1u;
      acc[ct][r] = bit ? e : 0.f;
    }
    s[r] = acc_s;
  }
#pragma unroll
  for (int i = 1; i < 16; i <<= 1)
#pragma unroll
    for (int r = 0; r < 4; ++r) s[r] += __shfl_xor(s[r], i);

  float inv[4];
#pragma unroll
  for (int r = 0; r < 4; ++r) inv[r] = dropscale / s[r];

  // PV with chunked P transpose (96 cols per chunk) — FULLY UNROLLED
  f32x4 cd[2] = {{0.f,0.f,0.f,0.f},{0.f,0.f,0.f,0.f}};
#pragma unroll
  for (int chunk = 0; chunk < 3; ++chunk) {
#pragma unroll
    for (int cc = 0; cc < 6; ++cc) {
      const int ct = chunk * 6 + cc;
#pragma unroll
      for (int r = 0; r < 4; ++r)
        wlds[wid][lg * 4 + r][cc * 16 + lr] = (bf16_t)(acc[ct][r] * inv[r]);
    }
    // waves are independent; ds ops within a wave are ordered by lgkmcnt,
    // and each wave only touches wlds[wid] -> no barrier needed.
#pragma unroll
    for (int dt = 0; dt < 2; ++dt)
#pragma unroll
      for (int k3 = 0; k3 < 3; ++k3) {
        bf16x8 aw = *reinterpret_cast<const bf16x8*>(&wlds[wid][lr][k3 * 32 + lg * 8]);
        bf16x8 bv = *reinterpret_cast<const bf16x8*>(
            Vh + (dt * 16 + lr) * N_ + chunk * 96 + k3 * 32 + lg * 8);
        cd[dt] = __builtin_amdgcn_mfma_f32_16x16x32_bf16(aw, bv, cd[dt], 0, 0, 0);
      }
  }

#pragma unroll
  for (int dt = 0; dt < 2; ++dt) {
    size_t obase = ((size_t)bt * N_ + q0) * D_ + h * HD_ + dt * 16 + lr;
#pragma unroll
    for (int r = 0; r < 4; ++r)
      CTX[obase + (size_t)r * D_] = (bf16_t)cd[dt][r];
  }
}

// ---------------------------------------------------------------- kernel 3
__global__ __launch_bounds__(256) void out_proj(
    const bf16_t* __restrict__ CTX, const bf16_t* __restrict__ Wt,
    const float* __restrict__ bo, float* __restrict__ out) {
  const int lane = threadIdx.x & 63;
  const int wid  = threadIdx.x >> 6;
  const int lr   = lane & 15, lg = lane >> 4;
  const int tokbase = blockIdx.x * 64 + wid * 16;
  const bf16_t* Wo = Wt + 3 * 16384;

  bf16x8 a[4];
#pragma unroll
  for (int ks = 0; ks < 4; ++ks)
    a[ks] = *reinterpret_cast<const bf16x8*>(
        CTX + (size_t)(tokbase + lr) * D_ + ks * 32 + lg * 8);

  const int tok0 = tokbase + lg * 4;
#pragma unroll
  for (int ct = 0; ct < 8; ++ct) {
    const int col = ct * 16 + lr;
    f32x4 acc = {0.f, 0.f, 0.f, 0.f};
#pragma unroll
    for (int ks = 0; ks < 4; ++ks) {
      bf16x8 b = *reinterpret_cast<const bf16x8*>(Wo + col * D_ + ks * 32 + lg * 8);
      acc = __builtin_amdgcn_mfma_f32_16x16x32_bf16(a[ks], b, acc, 0, 0, 0);
    }
    const float bias = bo[col];
    size_t ob = (size_t)tok0 * D_ + col;
#pragma unroll
    for (int r = 0; r < 4; ++r) out[ob + (size_t)r * D_] = acc[r] + bias;
  }
}

// ---------------------------------------------------------------- launcher
extern "C" void kernel_launch(void* const* d_in, const int* in_sizes, int n_in,
                              void* d_out, int out_size, void* d_ws, size_t ws_size,
                              hipStream_t stream) {
  (void)in_sizes; (void)n_in; (void)out_size; (void)ws_size;
  const float* x  = (const float*)d_in[0];
  const float* Wq = (const float*)d_in[1];
  const float* Wk = (const float*)d_in[2];
  const float* Wv = (const float*)d_in[3];
  const float* Wo = (const float*)d_in[4];
  const float* bo = (const float*)d_in[5];
  const float* du = (const float*)d_in[6];
  const int*   nx = (const int*)d_in[7];

  char* ws = (char*)d_ws;
  bf16_t* Qb   = (bf16_t*)(ws + OFF_Q);
  bf16_t* Kb   = (bf16_t*)(ws + OFF_K);
  bf16_t* VTb  = (bf16_t*)(ws + OFF_VT);
  bf16_t* CTXb = (bf16_t*)(ws + OFF_CTX);
  bf16_t* Wt   = (bf16_t*)(ws + OFF_WT);
  unsigned long long* maskG = (unsigned long long*)(ws + OFF_MB);

  build_mask<<<2048, 256, 0, stream>>>(du, nx, maskG);
  prep_weights<<<256, 256, 0, stream>>>(Wq, Wk, Wv, Wo, Wt);
  qkv_proj<<<NTOK / 64, 256, 0, stream>>>(x, Wt, Qb, Kb, VTb);
  attn<<<(BTH * 18) / 4, 256, 0, stream>>>(Qb, Kb, VTb, maskG, nx, CTXb);
  out_proj<<<NTOK / 64, 256, 0, stream>>>(CTXb, Wt, bo, (float*)d_out);
}